// Round 7
// baseline (1024.874 us; speedup 1.0000x reference)
//
#include <hip/hip_runtime.h>

typedef unsigned short u16;
typedef __bf16 bf16x8 __attribute__((ext_vector_type(8)));
typedef float f32x4 __attribute__((ext_vector_type(4)));

#define B_SZ   4096
#define H_NUM  32
#define F_DIM  1024
#define NTOT   (H_NUM * F_DIM)   // 32768
#define N_CAT  8
#define CAT_D  16
#define N_CONT 24
#define LN_EPS 1e-5f
#define NSTRIP (NTOT / 128)      // 256 n-strips in the GEMM

__device__ __forceinline__ u16 f2bf(float f) {
    unsigned int u = __builtin_bit_cast(unsigned int, f);
    unsigned int r = (u + 0x7FFFu + ((u >> 16) & 1u)) >> 16;
    return (u16)r;
}

__device__ __forceinline__ void gl2lds16(const void* g, void* l) {
    __builtin_amdgcn_global_load_lds(
        (const __attribute__((address_space(1))) void*)g,
        (__attribute__((address_space(3))) void*)l,
        16, 0, 0);
}

__device__ __forceinline__ float wave_sum(float v) {
#pragma unroll
    for (int o = 32; o; o >>= 1) v += __shfl_xor(v, o);
    return v;
}

// ---------------- z f32 -> bf16 ----------------
__global__ __launch_bounds__(256) void zconv(const float* __restrict__ z,
                                             u16* __restrict__ zb) {
    int i = blockIdx.x * 256 + threadIdx.x;      // one float4 per thread
    float4 v = ((const float4*)z)[i];
    ushort4 o;
    o.x = f2bf(v.x); o.y = f2bf(v.y); o.z = f2bf(v.z); o.w = f2bf(v.w);
    ((ushort4*)zb)[i] = o;
}

// ---------------- W_proj [h][f][d] f32 -> Wt [h][d][f] bf16 ----------------
__global__ __launch_bounds__(256) void transpose_w(const float* __restrict__ W,
                                                   u16* __restrict__ Wt) {
    __shared__ u16 tile[64][72];
    const int h = blockIdx.z;
    const int f0 = blockIdx.x * 64;
    const int d0 = blockIdx.y * 64;
    const float* Wh = W + (size_t)h * F_DIM * F_DIM;
    u16* Wth = Wt + (size_t)h * F_DIM * F_DIM;
    const int t = threadIdx.x;

#pragma unroll
    for (int i = 0; i < 4; ++i) {
        int idx = i * 256 + t;        // 0..1023
        int fr = idx >> 4;            // 0..63
        int c4 = idx & 15;            // 0..15
        float4 v = *(const float4*)(Wh + (size_t)(f0 + fr) * F_DIM + d0 + c4 * 4);
        tile[fr][c4 * 4 + 0] = f2bf(v.x);
        tile[fr][c4 * 4 + 1] = f2bf(v.y);
        tile[fr][c4 * 4 + 2] = f2bf(v.z);
        tile[fr][c4 * 4 + 3] = f2bf(v.w);
    }
    __syncthreads();
#pragma unroll
    for (int i = 0; i < 2; ++i) {
        int idx = i * 256 + t;        // 0..511
        int dr = idx >> 3;            // 0..63
        int c8 = idx & 7;             // 0..7
        __attribute__((aligned(16))) u16 tmp[8];
#pragma unroll
        for (int j = 0; j < 8; ++j) tmp[j] = tile[c8 * 8 + j][dr];
        *(uint4*)(Wth + (size_t)(d0 + dr) * F_DIM + f0 + c8 * 8) = *(const uint4*)tmp;
    }
}

// ---------------- GEMM (2-phase double-buffered) + per-block LN partials ----------------
// Ordering: xcd = wg&7 owns n-strips [xcd*32, xcd*32+32); within an XCD blocks
// walk 8x8 super-squares (m fastest) -> B slice hot in local L2, A slice L3-shared.
// K-loop: STAGE(next) issued before COMPUTE(cur); one __syncthreads (vmcnt0+barrier)
// per K-step so staging latency hides under the 32-MFMA compute phase (T3 min-2ph).
__global__ __launch_bounds__(256) void gemm_bt(const u16* __restrict__ A,
                                               const u16* __restrict__ Bt,
                                               const float* __restrict__ bproj,
                                               float* __restrict__ C,
                                               float* __restrict__ psum,
                                               float* __restrict__ psumsq) {
    __shared__ u16 sA[2][128 * 64];
    __shared__ u16 sB[2][128 * 64];
    __shared__ float sred[2][128];
    __shared__ float s2red[2][128];
    const int t = threadIdx.x;
    const int wid = t >> 6;
    const int lane = t & 63;
    const int l16 = lane & 15;
    const int lk = lane >> 4;
    const int wr = wid >> 1;
    const int wc = wid & 1;

    const int wg = blockIdx.x;
    const int xcd = wg & 7;
    const int local = wg >> 3;                 // 0..1023 within XCD
    const int sq = local >> 6;                 // 16 super-squares (4 msq x 4 nsq)
    const int within = local & 63;             // 8m x 8n inside a square
    const int m0 = (((sq & 3) << 3) + (within & 7)) * 128;
    const int n0 = ((xcd << 5) + ((sq >> 2) << 3) + (within >> 3)) * 128;

    f32x4 acc[4][4];
    const f32x4 zero = {0.f, 0.f, 0.f, 0.f};
#pragma unroll
    for (int m = 0; m < 4; ++m)
#pragma unroll
        for (int n = 0; n < 4; ++n) acc[m][n] = zero;

    auto stage = [&](int buf, int k0) {
#pragma unroll
        for (int q2 = 0; q2 < 4; ++q2) {
            int ci = q2 * 256 + t;
            int r = ci >> 3, c8 = ci & 7;
            gl2lds16(A + ((size_t)(m0 + r) << 10) + k0 + c8 * 8,
                     &sA[buf][(q2 * 256 + (wid << 6)) * 8]);
        }
#pragma unroll
        for (int q2 = 0; q2 < 4; ++q2) {
            int ci = q2 * 256 + t;
            int r = ci >> 3, c8 = ci & 7;
            gl2lds16(Bt + ((size_t)(n0 + r) << 10) + k0 + c8 * 8,
                     &sB[buf][(q2 * 256 + (wid << 6)) * 8]);
        }
    };

    auto compute = [&](int buf) {
#pragma unroll
        for (int kk = 0; kk < 64; kk += 32) {
            bf16x8 a[4], bfv[4];
#pragma unroll
            for (int m = 0; m < 4; ++m)
                a[m] = *(const bf16x8*)(&sA[buf][(wr * 64 + m * 16 + l16) * 64 + kk + lk * 8]);
#pragma unroll
            for (int n = 0; n < 4; ++n)
                bfv[n] = *(const bf16x8*)(&sB[buf][(wc * 64 + n * 16 + l16) * 64 + kk + lk * 8]);
#pragma unroll
            for (int m = 0; m < 4; ++m)
#pragma unroll
                for (int n = 0; n < 4; ++n)
                    acc[m][n] = __builtin_amdgcn_mfma_f32_16x16x32_bf16(a[m], bfv[n], acc[m][n], 0, 0, 0);
        }
    };

    stage(0, 0);
    __syncthreads();
    int cur = 0;
    for (int it = 0; it < 15; ++it) {
        stage(cur ^ 1, (it + 1) * 64);   // issue next-tile loads first
        compute(cur);                     // overlap: MFMA while loads in flight
        __syncthreads();                  // vmcnt(0)+lgkmcnt(0)+barrier, once per K-step
        cur ^= 1;
    }
    compute(cur);                         // last tile, no prefetch

    // epilogue: C-write (m-outer so each wave's 4 n-stores form 256B contiguous
    // runs -> full-line write combining) + per-row (sum, sumsq) partials
    float bias[4];
#pragma unroll
    for (int n = 0; n < 4; ++n) bias[n] = bproj[n0 + wc * 64 + n * 16 + l16];

    float sm[4][4], s2m[4][4];
#pragma unroll
    for (int m = 0; m < 4; ++m)
#pragma unroll
        for (int j = 0; j < 4; ++j) { sm[m][j] = 0.f; s2m[m][j] = 0.f; }

#pragma unroll
    for (int m = 0; m < 4; ++m) {
        int rbase = m0 + wr * 64 + m * 16 + lk * 4;
#pragma unroll
        for (int j = 0; j < 4; ++j) {
            float* crow = C + (size_t)(rbase + j) * NTOT + n0 + wc * 64 + l16;
#pragma unroll
            for (int n = 0; n < 4; ++n) {
                float v = acc[m][n][j] + bias[n];
                crow[n * 16] = v;
                sm[m][j] += v;
                s2m[m][j] += v * v;
            }
        }
    }
    // reduce over the 16 l16 lanes (same rows, different cols)
#pragma unroll
    for (int o = 1; o < 16; o <<= 1) {
#pragma unroll
        for (int m = 0; m < 4; ++m)
#pragma unroll
            for (int j = 0; j < 4; ++j) {
                sm[m][j] += __shfl_xor(sm[m][j], o);
                s2m[m][j] += __shfl_xor(s2m[m][j], o);
            }
    }
    if (l16 == 0) {
#pragma unroll
        for (int m = 0; m < 4; ++m)
#pragma unroll
            for (int j = 0; j < 4; ++j) {
                int r = wr * 64 + m * 16 + lk * 4 + j;
                sred[wc][r] = sm[m][j];
                s2red[wc][r] = s2m[m][j];
            }
    }
    __syncthreads();
    // psum layout [strip][b]: 128 consecutive f32 per block -> full-line writes,
    // no write-allocate RMW fetch (was [b][strip], 4B stores at 1KB stride).
    if (t < 128) {
        int strip = n0 >> 7;
        psum[(size_t)strip * B_SZ + m0 + t] = sred[0][t] + sred[1][t];
        psumsq[(size_t)strip * B_SZ + m0 + t] = s2red[0][t] + s2red[1][t];
    }
}

// ---------------- finalize LN stats from partials (psum layout [strip][b]) ----------------
// 64 blocks x 256 threads; block handles 64 consecutive b, lane-adjacent b -> coalesced.
__global__ __launch_bounds__(256) void ln_finalize(const float* __restrict__ psum,
                                                   const float* __restrict__ psumsq,
                                                   float* __restrict__ murs) {
    const int t = threadIdx.x;
    const int b0 = blockIdx.x * 64;
    const int tb = t & 63;            // which b
    const int tg = t >> 6;            // strip group 0..3
    float s = 0.f, s2 = 0.f;
    for (int sidx = tg; sidx < NSTRIP; sidx += 4) {
        s += psum[(size_t)sidx * B_SZ + b0 + tb];
        s2 += psumsq[(size_t)sidx * B_SZ + b0 + tb];
    }
    __shared__ float r1[4][64], r2[4][64];
    r1[tg][tb] = s;
    r2[tg][tb] = s2;
    __syncthreads();
    if (t < 64) {
        float S = r1[0][t] + r1[1][t] + r1[2][t] + r1[3][t];
        float S2 = r2[0][t] + r2[1][t] + r2[2][t] + r2[3][t];
        float m = S / (float)NTOT;
        float var = S2 / (float)NTOT - m * m;
        murs[b0 + t] = m;
        murs[B_SZ + b0 + t] = rsqrtf(var + LN_EPS);
    }
}

// ---------------- normalize + relu + heads: one 256-thread block per b ----------------
// Iteration k covers head k exactly: i = 256k + t (coalesced float4s).
__global__ __launch_bounds__(256) void headsG(float* __restrict__ lat_base,
                                              const float* __restrict__ murs,
                                              const float* __restrict__ lnw,
                                              const float* __restrict__ lnb,
                                              const float* __restrict__ Wcat,
                                              const float* __restrict__ bcat,
                                              const float* __restrict__ Wcont,
                                              const float* __restrict__ bcont,
                                              float* __restrict__ pcat,
                                              float* __restrict__ pcont) {
    const int b = blockIdx.x;
    const int t = threadIdx.x;
    const int lane = t & 63;
    const int w4 = t >> 6;                    // wave 0..3
    const float mu = murs[b];
    const float rs = murs[B_SZ + b];
    float4* lat4 = (float4*)(lat_base + (size_t)b * NTOT);
    const float4* lnw4 = (const float4*)lnw;
    const float4* lnb4 = (const float4*)lnb;
    const float4* wcont4 = (const float4*)Wcont;

    __shared__ float4 sy4[2][256];            // double-buffered head row of y
    __shared__ float cred[4][N_CAT][CAT_D];   // per-wave cat partials
    __shared__ float nred[N_CONT][4];         // per-wave cont partials

    // ---- categorical heads (k = h = 0..7): stage y in LDS, short-reduce GEMV ----
    for (int k = 0; k < N_CAT; ++k) {
        const int i = (k << 8) + t;
        float4 x = lat4[i];
        float4 w = lnw4[i];
        float4 bv = lnb4[i];
        float4 yo;
        yo.x = fmaxf(0.f, (x.x - mu) * rs * w.x + bv.x);
        yo.y = fmaxf(0.f, (x.y - mu) * rs * w.y + bv.y);
        yo.z = fmaxf(0.f, (x.z - mu) * rs * w.z + bv.z);
        yo.w = fmaxf(0.f, (x.w - mu) * rs * w.w + bv.w);
        lat4[i] = yo;
        sy4[k & 1][t] = yo;
        __syncthreads();

        const int c = t & 15;                 // category column
        const int g = t >> 4;                 // f-group: f = g*64 .. g*64+63
        const float* Wc = Wcat + (size_t)k * F_DIM * CAT_D + c;
        float acc = 0.f;
#pragma unroll
        for (int j = 0; j < 16; ++j) {
            float4 yv = sy4[k & 1][g * 16 + j];
            int fb = (g * 64 + j * 4) * CAT_D;
            acc += yv.x * Wc[fb] + yv.y * Wc[fb + CAT_D] +
                   yv.z * Wc[fb + 2 * CAT_D] + yv.w * Wc[fb + 3 * CAT_D];
        }
        acc += __shfl_xor(acc, 16);
        acc += __shfl_xor(acc, 32);
        if (lane < 16) cred[w4][k][lane] = acc;
        // no second barrier: next iteration writes the other sy4 buffer,
        // and the k+2 overwrite is fenced by the k+1 barrier.
    }

    // ---- continuous heads (k = 8..31): barrier-free streaming ----
#pragma unroll 2
    for (int k = N_CAT; k < H_NUM; ++k) {
        const int i = (k << 8) + t;
        float4 x = lat4[i];
        float4 w = lnw4[i];
        float4 bv = lnb4[i];
        float4 wv = wcont4[((k - N_CAT) << 8) + t];
        float4 yo;
        yo.x = fmaxf(0.f, (x.x - mu) * rs * w.x + bv.x);
        yo.y = fmaxf(0.f, (x.y - mu) * rs * w.y + bv.y);
        yo.z = fmaxf(0.f, (x.z - mu) * rs * w.z + bv.z);
        yo.w = fmaxf(0.f, (x.w - mu) * rs * w.w + bv.w);
        lat4[i] = yo;
        float part = yo.x * wv.x + yo.y * wv.y + yo.z * wv.z + yo.w * wv.w;
        part = wave_sum(part);
        if (lane == 0) nred[k - N_CAT][w4] = part;
    }
    __syncthreads();

    // ---- finalize ----
    if (t < 128) {                            // cat softmax: h = t>>4, c = t&15
        const int h = t >> 4, c = t & 15;
        float lg = cred[0][h][c] + cred[1][h][c] + cred[2][h][c] + cred[3][h][c] +
                   bcat[h * CAT_D + c];
        float mx = lg;
#pragma unroll
        for (int o = 8; o; o >>= 1) mx = fmaxf(mx, __shfl_xor(mx, o, 16));
        float e = __expf(lg - mx);
        float sm2 = e;
#pragma unroll
        for (int o = 8; o; o >>= 1) sm2 += __shfl_xor(sm2, o, 16);
        pcat[(size_t)b * (N_CAT * CAT_D) + t] = e / sm2;
    } else if (t >= 128 && t < 128 + N_CONT) {
        const int ci = t - 128;
        pcont[(size_t)b * N_CONT + ci] =
            nred[ci][0] + nred[ci][1] + nred[ci][2] + nred[ci][3] + bcont[ci];
    }
}

extern "C" void kernel_launch(void* const* d_in, const int* in_sizes, int n_in,
                              void* d_out, int out_size, void* d_ws, size_t ws_size,
                              hipStream_t stream) {
    const float* z     = (const float*)d_in[0];
    // d_in[1] = edge (unused by reference computation)
    const float* Wp    = (const float*)d_in[2];
    const float* bp    = (const float*)d_in[3];
    const float* lnw   = (const float*)d_in[4];
    const float* lnb   = (const float*)d_in[5];
    const float* Wcat  = (const float*)d_in[6];
    const float* bcat  = (const float*)d_in[7];
    const float* Wcont = (const float*)d_in[8];
    const float* bcont = (const float*)d_in[9];

    float* out    = (float*)d_out;
    float* pcat   = out;                                   // [4096, 8, 16]
    float* pcont  = out + (size_t)B_SZ * N_CAT * CAT_D;    // [4096, 24, 1]
    float* latent = pcont + (size_t)B_SZ * N_CONT;         // [4096, 32, 1024]

    u16* zb     = (u16*)d_ws;                              // 4096*1024 bf16 (8 MB)
    u16* Wt     = zb + (size_t)B_SZ * F_DIM;               // 32768*1024 bf16 (64 MB)
    float* murs = (float*)(Wt + (size_t)NTOT * F_DIM);     // 2*4096 f32
    float* psum   = murs + 2 * B_SZ;                       // [256][4096] f32 (4 MB)
    float* psumsq = psum + (size_t)B_SZ * NSTRIP;          // [256][4096] f32 (4 MB)

    zconv<<<dim3(B_SZ * F_DIM / 1024), 256, 0, stream>>>(z, zb);
    transpose_w<<<dim3(16, 16, 32), 256, 0, stream>>>(Wp, Wt);
    gemm_bt<<<dim3(NSTRIP * (B_SZ / 128)), 256, 0, stream>>>(zb, Wt, bp, latent, psum, psumsq);
    ln_finalize<<<dim3(B_SZ / 64), 256, 0, stream>>>(psum, psumsq, murs);
    headsG<<<dim3(B_SZ), 256, 0, stream>>>(latent, murs, lnw, lnb, Wcat, bcat,
                                           Wcont, bcont, pcat, pcont);
}

// Round 8
// 884.654 us; speedup vs baseline: 1.1585x; 1.1585x over previous
//
#include <hip/hip_runtime.h>

typedef unsigned short u16;
typedef __bf16 bf16x8 __attribute__((ext_vector_type(8)));
typedef float f32x4 __attribute__((ext_vector_type(4)));

#define B_SZ   4096
#define H_NUM  32
#define F_DIM  1024
#define NTOT   (H_NUM * F_DIM)   // 32768
#define N_CAT  8
#define CAT_D  16
#define N_CONT 24
#define LN_EPS 1e-5f
#define NSTRIP (NTOT / 128)      // 256 n-strips in the GEMM

__device__ __forceinline__ u16 f2bf(float f) {
    unsigned int u = __builtin_bit_cast(unsigned int, f);
    unsigned int r = (u + 0x7FFFu + ((u >> 16) & 1u)) >> 16;
    return (u16)r;
}

__device__ __forceinline__ float bf2f(u16 v) {
    unsigned int u = ((unsigned int)v) << 16;
    return __builtin_bit_cast(float, u);
}

__device__ __forceinline__ void gl2lds16(const void* g, void* l) {
    __builtin_amdgcn_global_load_lds(
        (const __attribute__((address_space(1))) void*)g,
        (__attribute__((address_space(3))) void*)l,
        16, 0, 0);
}

__device__ __forceinline__ float wave_sum(float v) {
#pragma unroll
    for (int o = 32; o; o >>= 1) v += __shfl_xor(v, o);
    return v;
}

// ---------------- z f32 -> bf16 ----------------
__global__ __launch_bounds__(256) void zconv(const float* __restrict__ z,
                                             u16* __restrict__ zb) {
    int i = blockIdx.x * 256 + threadIdx.x;      // one float4 per thread
    float4 v = ((const float4*)z)[i];
    ushort4 o;
    o.x = f2bf(v.x); o.y = f2bf(v.y); o.z = f2bf(v.z); o.w = f2bf(v.w);
    ((ushort4*)zb)[i] = o;
}

// ---------------- W_proj [h][f][d] f32 -> Wt [h][d][f] bf16 ----------------
__global__ __launch_bounds__(256) void transpose_w(const float* __restrict__ W,
                                                   u16* __restrict__ Wt) {
    __shared__ u16 tile[64][72];
    const int h = blockIdx.z;
    const int f0 = blockIdx.x * 64;
    const int d0 = blockIdx.y * 64;
    const float* Wh = W + (size_t)h * F_DIM * F_DIM;
    u16* Wth = Wt + (size_t)h * F_DIM * F_DIM;
    const int t = threadIdx.x;

#pragma unroll
    for (int i = 0; i < 4; ++i) {
        int idx = i * 256 + t;        // 0..1023
        int fr = idx >> 4;            // 0..63
        int c4 = idx & 15;            // 0..15
        float4 v = *(const float4*)(Wh + (size_t)(f0 + fr) * F_DIM + d0 + c4 * 4);
        tile[fr][c4 * 4 + 0] = f2bf(v.x);
        tile[fr][c4 * 4 + 1] = f2bf(v.y);
        tile[fr][c4 * 4 + 2] = f2bf(v.z);
        tile[fr][c4 * 4 + 3] = f2bf(v.w);
    }
    __syncthreads();
#pragma unroll
    for (int i = 0; i < 2; ++i) {
        int idx = i * 256 + t;        // 0..511
        int dr = idx >> 3;            // 0..63
        int c8 = idx & 7;             // 0..7
        __attribute__((aligned(16))) u16 tmp[8];
#pragma unroll
        for (int j = 0; j < 8; ++j) tmp[j] = tile[c8 * 8 + j][dr];
        *(uint4*)(Wth + (size_t)(d0 + dr) * F_DIM + f0 + c8 * 8) = *(const uint4*)tmp;
    }
}

// ---------------- GEMM (single-buffer, R6 schedule) + LN partials ----------------
// BF=1: store pre-LN latent as bf16 to lat16 (heads re-normalizes); BF=0: f32 to latf.
template <int BF>
__global__ __launch_bounds__(256) void gemm_bt(const u16* __restrict__ A,
                                               const u16* __restrict__ Bt,
                                               const float* __restrict__ bproj,
                                               u16* __restrict__ lat16,
                                               float* __restrict__ latf,
                                               float* __restrict__ psum,
                                               float* __restrict__ psumsq) {
    __shared__ u16 sA[128 * 64];
    __shared__ u16 sB[128 * 64];
    __shared__ float sred[2][128];
    __shared__ float s2red[2][128];
    const int t = threadIdx.x;
    const int wid = t >> 6;
    const int lane = t & 63;
    const int l16 = lane & 15;
    const int lk = lane >> 4;
    const int wr = wid >> 1;
    const int wc = wid & 1;

    const int wg = blockIdx.x;
    const int xcd = wg & 7;
    const int local = wg >> 3;                 // 0..1023 within XCD
    const int sq = local >> 6;                 // 16 super-squares (4 msq x 4 nsq)
    const int within = local & 63;             // 8m x 8n inside a square
    const int m0 = (((sq & 3) << 3) + (within & 7)) * 128;
    const int n0 = ((xcd << 5) + ((sq >> 2) << 3) + (within >> 3)) * 128;

    f32x4 acc[4][4];
    const f32x4 zero = {0.f, 0.f, 0.f, 0.f};
#pragma unroll
    for (int m = 0; m < 4; ++m)
#pragma unroll
        for (int n = 0; n < 4; ++n) acc[m][n] = zero;

    for (int k0 = 0; k0 < 1024; k0 += 64) {
#pragma unroll
        for (int q2 = 0; q2 < 4; ++q2) {
            int ci = q2 * 256 + t;
            int r = ci >> 3, c8 = ci & 7;
            gl2lds16(A + ((size_t)(m0 + r) << 10) + k0 + c8 * 8,
                     sA + (size_t)(q2 * 256 + (wid << 6)) * 8);
        }
#pragma unroll
        for (int q2 = 0; q2 < 4; ++q2) {
            int ci = q2 * 256 + t;
            int r = ci >> 3, c8 = ci & 7;
            gl2lds16(Bt + ((size_t)(n0 + r) << 10) + k0 + c8 * 8,
                     sB + (size_t)(q2 * 256 + (wid << 6)) * 8);
        }
        __syncthreads();
#pragma unroll
        for (int kk = 0; kk < 64; kk += 32) {
            bf16x8 a[4], bfv[4];
#pragma unroll
            for (int m = 0; m < 4; ++m)
                a[m] = *(const bf16x8*)(sA + (wr * 64 + m * 16 + l16) * 64 + kk + lk * 8);
#pragma unroll
            for (int n = 0; n < 4; ++n)
                bfv[n] = *(const bf16x8*)(sB + (wc * 64 + n * 16 + l16) * 64 + kk + lk * 8);
#pragma unroll
            for (int m = 0; m < 4; ++m)
#pragma unroll
                for (int n = 0; n < 4; ++n)
                    acc[m][n] = __builtin_amdgcn_mfma_f32_16x16x32_bf16(a[m], bfv[n], acc[m][n], 0, 0, 0);
        }
        __syncthreads();
    }

    // epilogue: latent write (m-outer, contiguous 256B runs per wave) + LN partials
    float bias[4];
#pragma unroll
    for (int n = 0; n < 4; ++n) bias[n] = bproj[n0 + wc * 64 + n * 16 + l16];

    float sm[4][4], s2m[4][4];
#pragma unroll
    for (int m = 0; m < 4; ++m)
#pragma unroll
        for (int j = 0; j < 4; ++j) { sm[m][j] = 0.f; s2m[m][j] = 0.f; }

#pragma unroll
    for (int m = 0; m < 4; ++m) {
        int rbase = m0 + wr * 64 + m * 16 + lk * 4;
#pragma unroll
        for (int j = 0; j < 4; ++j) {
            size_t rowoff = (size_t)(rbase + j) * NTOT + n0 + wc * 64 + l16;
#pragma unroll
            for (int n = 0; n < 4; ++n) {
                float v = acc[m][n][j] + bias[n];
                if (BF) lat16[rowoff + n * 16] = f2bf(v);
                else    latf[rowoff + n * 16] = v;
                sm[m][j] += v;
                s2m[m][j] += v * v;
            }
        }
    }
    // reduce over the 16 l16 lanes (same rows, different cols)
#pragma unroll
    for (int o = 1; o < 16; o <<= 1) {
#pragma unroll
        for (int m = 0; m < 4; ++m)
#pragma unroll
            for (int j = 0; j < 4; ++j) {
                sm[m][j] += __shfl_xor(sm[m][j], o);
                s2m[m][j] += __shfl_xor(s2m[m][j], o);
            }
    }
    if (l16 == 0) {
#pragma unroll
        for (int m = 0; m < 4; ++m)
#pragma unroll
            for (int j = 0; j < 4; ++j) {
                int r = wr * 64 + m * 16 + lk * 4 + j;
                sred[wc][r] = sm[m][j];
                s2red[wc][r] = s2m[m][j];
            }
    }
    __syncthreads();
    // psum layout [strip][b]: 128 consecutive f32 per block -> full-line writes
    if (t < 128) {
        int strip = n0 >> 7;
        psum[(size_t)strip * B_SZ + m0 + t] = sred[0][t] + sred[1][t];
        psumsq[(size_t)strip * B_SZ + m0 + t] = s2red[0][t] + s2red[1][t];
    }
}

// ---------------- finalize LN stats from partials (psum layout [strip][b]) ----------------
__global__ __launch_bounds__(256) void ln_finalize(const float* __restrict__ psum,
                                                   const float* __restrict__ psumsq,
                                                   float* __restrict__ murs) {
    const int t = threadIdx.x;
    const int b0 = blockIdx.x * 64;
    const int tb = t & 63;            // which b
    const int tg = t >> 6;            // strip group 0..3
    float s = 0.f, s2 = 0.f;
    for (int sidx = tg; sidx < NSTRIP; sidx += 4) {
        s += psum[(size_t)sidx * B_SZ + b0 + tb];
        s2 += psumsq[(size_t)sidx * B_SZ + b0 + tb];
    }
    __shared__ float r1[4][64], r2[4][64];
    r1[tg][tb] = s;
    r2[tg][tb] = s2;
    __syncthreads();
    if (t < 64) {
        float S = r1[0][t] + r1[1][t] + r1[2][t] + r1[3][t];
        float S2 = r2[0][t] + r2[1][t] + r2[2][t] + r2[3][t];
        float m = S / (float)NTOT;
        float var = S2 / (float)NTOT - m * m;
        murs[b0 + t] = m;
        murs[B_SZ + b0 + t] = rsqrtf(var + LN_EPS);
    }
}

// ---------------- normalize + relu + heads: one 256-thread block per b ----------------
// BF=1: latin is bf16 pre-LN latent (ws); BF=0: latin is f32 pre-LN latent (=latout).
template <int BF>
__global__ __launch_bounds__(256) void headsG(const void* __restrict__ latin_,
                                              float* __restrict__ latout,
                                              const float* __restrict__ murs,
                                              const float* __restrict__ lnw,
                                              const float* __restrict__ lnb,
                                              const float* __restrict__ Wcat,
                                              const float* __restrict__ bcat,
                                              const float* __restrict__ Wcont,
                                              const float* __restrict__ bcont,
                                              float* __restrict__ pcat,
                                              float* __restrict__ pcont) {
    const int b = blockIdx.x;
    const int t = threadIdx.x;
    const int lane = t & 63;
    const int w4 = t >> 6;                    // wave 0..3
    const float mu = murs[b];
    const float rs = murs[B_SZ + b];
    const ushort4* lin16 = (const ushort4*)((const u16*)latin_ + (size_t)b * NTOT);
    const float4*  linf  = (const float4*)((const float*)latin_ + (size_t)b * NTOT);
    float4* lout4 = (float4*)(latout + (size_t)b * NTOT);
    const float4* lnw4 = (const float4*)lnw;
    const float4* lnb4 = (const float4*)lnb;
    const float4* wcont4 = (const float4*)Wcont;

    __shared__ float4 sy4[2][256];            // double-buffered head row of y
    __shared__ float cred[4][N_CAT][CAT_D];   // per-wave cat partials
    __shared__ float nred[N_CONT][4];         // per-wave cont partials

    // ---- categorical heads (k = h = 0..7): stage y in LDS, short-reduce GEMV ----
    for (int k = 0; k < N_CAT; ++k) {
        const int i = (k << 8) + t;
        float4 x;
        if (BF) {
            ushort4 xv = lin16[i];
            x.x = bf2f(xv.x); x.y = bf2f(xv.y); x.z = bf2f(xv.z); x.w = bf2f(xv.w);
        } else {
            x = linf[i];
        }
        float4 w = lnw4[i];
        float4 bv = lnb4[i];
        float4 yo;
        yo.x = fmaxf(0.f, (x.x - mu) * rs * w.x + bv.x);
        yo.y = fmaxf(0.f, (x.y - mu) * rs * w.y + bv.y);
        yo.z = fmaxf(0.f, (x.z - mu) * rs * w.z + bv.z);
        yo.w = fmaxf(0.f, (x.w - mu) * rs * w.w + bv.w);
        lout4[i] = yo;
        sy4[k & 1][t] = yo;
        __syncthreads();

        const int c = t & 15;                 // category column
        const int g = t >> 4;                 // f-group: f = g*64 .. g*64+63
        const float* Wc = Wcat + (size_t)k * F_DIM * CAT_D + c;
        float acc = 0.f;
#pragma unroll
        for (int j = 0; j < 16; ++j) {
            float4 yv = sy4[k & 1][g * 16 + j];
            int fb = (g * 64 + j * 4) * CAT_D;
            acc += yv.x * Wc[fb] + yv.y * Wc[fb + CAT_D] +
                   yv.z * Wc[fb + 2 * CAT_D] + yv.w * Wc[fb + 3 * CAT_D];
        }
        acc += __shfl_xor(acc, 16);
        acc += __shfl_xor(acc, 32);
        if (lane < 16) cred[w4][k][lane] = acc;
        // no second barrier: next iteration writes the other sy4 buffer,
        // and the k+2 overwrite is fenced by the k+1 barrier.
    }

    // ---- continuous heads (k = 8..31): barrier-free streaming ----
#pragma unroll 2
    for (int k = N_CAT; k < H_NUM; ++k) {
        const int i = (k << 8) + t;
        float4 x;
        if (BF) {
            ushort4 xv = lin16[i];
            x.x = bf2f(xv.x); x.y = bf2f(xv.y); x.z = bf2f(xv.z); x.w = bf2f(xv.w);
        } else {
            x = linf[i];
        }
        float4 w = lnw4[i];
        float4 bv = lnb4[i];
        float4 wv = wcont4[((k - N_CAT) << 8) + t];
        float4 yo;
        yo.x = fmaxf(0.f, (x.x - mu) * rs * w.x + bv.x);
        yo.y = fmaxf(0.f, (x.y - mu) * rs * w.y + bv.y);
        yo.z = fmaxf(0.f, (x.z - mu) * rs * w.z + bv.z);
        yo.w = fmaxf(0.f, (x.w - mu) * rs * w.w + bv.w);
        lout4[i] = yo;
        float part = yo.x * wv.x + yo.y * wv.y + yo.z * wv.z + yo.w * wv.w;
        part = wave_sum(part);
        if (lane == 0) nred[k - N_CAT][w4] = part;
    }
    __syncthreads();

    // ---- finalize ----
    if (t < 128) {                            // cat softmax: h = t>>4, c = t&15
        const int h = t >> 4, c = t & 15;
        float lg = cred[0][h][c] + cred[1][h][c] + cred[2][h][c] + cred[3][h][c] +
                   bcat[h * CAT_D + c];
        float mx = lg;
#pragma unroll
        for (int o = 8; o; o >>= 1) mx = fmaxf(mx, __shfl_xor(mx, o, 16));
        float e = __expf(lg - mx);
        float sm2 = e;
#pragma unroll
        for (int o = 8; o; o >>= 1) sm2 += __shfl_xor(sm2, o, 16);
        pcat[(size_t)b * (N_CAT * CAT_D) + t] = e / sm2;
    } else if (t >= 128 && t < 128 + N_CONT) {
        const int ci = t - 128;
        pcont[(size_t)b * N_CONT + ci] =
            nred[ci][0] + nred[ci][1] + nred[ci][2] + nred[ci][3] + bcont[ci];
    }
}

extern "C" void kernel_launch(void* const* d_in, const int* in_sizes, int n_in,
                              void* d_out, int out_size, void* d_ws, size_t ws_size,
                              hipStream_t stream) {
    const float* z     = (const float*)d_in[0];
    // d_in[1] = edge (unused by reference computation)
    const float* Wp    = (const float*)d_in[2];
    const float* bp    = (const float*)d_in[3];
    const float* lnw   = (const float*)d_in[4];
    const float* lnb   = (const float*)d_in[5];
    const float* Wcat  = (const float*)d_in[6];
    const float* bcat  = (const float*)d_in[7];
    const float* Wcont = (const float*)d_in[8];
    const float* bcont = (const float*)d_in[9];

    float* out    = (float*)d_out;
    float* pcat   = out;                                   // [4096, 8, 16]
    float* pcont  = out + (size_t)B_SZ * N_CAT * CAT_D;    // [4096, 24, 1]
    float* latent = pcont + (size_t)B_SZ * N_CONT;         // [4096, 32, 1024]

    u16* zb     = (u16*)d_ws;                              // 8 MB
    u16* Wt     = zb + (size_t)B_SZ * F_DIM;               // 64 MB
    float* murs = (float*)(Wt + (size_t)NTOT * F_DIM);     // 32 KB
    float* psum   = murs + 2 * B_SZ;                       // [256][4096] 4 MB
    float* psumsq = psum + (size_t)B_SZ * NSTRIP;          // 4 MB
    u16* lat16  = (u16*)(psumsq + (size_t)B_SZ * NSTRIP);  // 256 MB (optional)

    const size_t need = (size_t)((char*)(lat16 + (size_t)B_SZ * NTOT) - (char*)d_ws);
    const bool usebf = ws_size >= need;

    zconv<<<dim3(B_SZ * F_DIM / 1024), 256, 0, stream>>>(z, zb);
    transpose_w<<<dim3(16, 16, 32), 256, 0, stream>>>(Wp, Wt);
    if (usebf) {
        gemm_bt<1><<<dim3(NSTRIP * (B_SZ / 128)), 256, 0, stream>>>(
            zb, Wt, bp, lat16, nullptr, psum, psumsq);
        ln_finalize<<<dim3(B_SZ / 64), 256, 0, stream>>>(psum, psumsq, murs);
        headsG<1><<<dim3(B_SZ), 256, 0, stream>>>(lat16, latent, murs, lnw, lnb,
                                                  Wcat, bcat, Wcont, bcont, pcat, pcont);
    } else {
        gemm_bt<0><<<dim3(NSTRIP * (B_SZ / 128)), 256, 0, stream>>>(
            zb, Wt, bp, nullptr, latent, psum, psumsq);
        ln_finalize<<<dim3(B_SZ / 64), 256, 0, stream>>>(psum, psumsq, murs);
        headsG<0><<<dim3(B_SZ), 256, 0, stream>>>(latent, latent, murs, lnw, lnb,
                                                  Wcat, bcat, Wcont, bcont, pcat, pcont);
    }
}

// Round 9
// 761.301 us; speedup vs baseline: 1.3462x; 1.1620x over previous
//
#include <hip/hip_runtime.h>

typedef unsigned short u16;
typedef __bf16 bf16x8 __attribute__((ext_vector_type(8)));
typedef float f32x4 __attribute__((ext_vector_type(4)));

#define B_SZ   4096
#define H_NUM  32
#define F_DIM  1024
#define NTOT   (H_NUM * F_DIM)   // 32768
#define N_CAT  8
#define CAT_D  16
#define N_CONT 24
#define LN_EPS 1e-5f
#define NSTRIP 128               // 256-col strips in the 256^2 GEMM

__device__ __forceinline__ u16 f2bf(float f) {
    unsigned int u = __builtin_bit_cast(unsigned int, f);
    unsigned int r = (u + 0x7FFFu + ((u >> 16) & 1u)) >> 16;
    return (u16)r;
}

__device__ __forceinline__ float bf2f(u16 v) {
    unsigned int u = ((unsigned int)v) << 16;
    return __builtin_bit_cast(float, u);
}

__device__ __forceinline__ void gl2lds16(const void* g, void* l) {
    __builtin_amdgcn_global_load_lds(
        (const __attribute__((address_space(1))) void*)g,
        (__attribute__((address_space(3))) void*)l,
        16, 0, 0);
}

__device__ __forceinline__ float wave_sum(float v) {
#pragma unroll
    for (int o = 32; o; o >>= 1) v += __shfl_xor(v, o);
    return v;
}

// ---------------- z f32 -> bf16 ----------------
__global__ __launch_bounds__(256) void zconv(const float* __restrict__ z,
                                             u16* __restrict__ zb) {
    int i = blockIdx.x * 256 + threadIdx.x;      // one float4 per thread
    float4 v = ((const float4*)z)[i];
    ushort4 o;
    o.x = f2bf(v.x); o.y = f2bf(v.y); o.z = f2bf(v.z); o.w = f2bf(v.w);
    ((ushort4*)zb)[i] = o;
}

// ---------------- W_proj [h][f][d] f32 -> Wt [h][d][f] bf16 ----------------
__global__ __launch_bounds__(256) void transpose_w(const float* __restrict__ W,
                                                   u16* __restrict__ Wt) {
    __shared__ u16 tile[64][72];
    const int h = blockIdx.z;
    const int f0 = blockIdx.x * 64;
    const int d0 = blockIdx.y * 64;
    const float* Wh = W + (size_t)h * F_DIM * F_DIM;
    u16* Wth = Wt + (size_t)h * F_DIM * F_DIM;
    const int t = threadIdx.x;

#pragma unroll
    for (int i = 0; i < 4; ++i) {
        int idx = i * 256 + t;        // 0..1023
        int fr = idx >> 4;            // 0..63
        int c4 = idx & 15;            // 0..15
        float4 v = *(const float4*)(Wh + (size_t)(f0 + fr) * F_DIM + d0 + c4 * 4);
        tile[fr][c4 * 4 + 0] = f2bf(v.x);
        tile[fr][c4 * 4 + 1] = f2bf(v.y);
        tile[fr][c4 * 4 + 2] = f2bf(v.z);
        tile[fr][c4 * 4 + 3] = f2bf(v.w);
    }
    __syncthreads();
#pragma unroll
    for (int i = 0; i < 2; ++i) {
        int idx = i * 256 + t;        // 0..511
        int dr = idx >> 3;            // 0..63
        int c8 = idx & 7;             // 0..7
        __attribute__((aligned(16))) u16 tmp[8];
#pragma unroll
        for (int j = 0; j < 8; ++j) tmp[j] = tile[c8 * 8 + j][dr];
        *(uint4*)(Wth + (size_t)(d0 + dr) * F_DIM + f0 + c8 * 8) = *(const uint4*)tmp;
    }
}

// ---------------- GEMM 256^2, 8 waves, 2-Ktile LDS dbuf, XOR-swizzled ----------------
// LDS (dynamic, 128 KiB): u16 [buf2][AB2][half2][8192]; byte = buf*65536+ab*32768+half*16384.
// Swizzle (both sides): within a 16KB half, byte off o -> o ^ (((o>>7)&7)<<4).
// Staged via global_load_lds with pre-swizzled SOURCE (linear LDS dest), read with
// swizzled ds_read addr; (row&7)-XOR spreads the 16 l16-lanes over 8 16B slots -> 2-way.
// Schedule: K-tile kt computed in 4 quadrant-phases; kt+1's 4 half-tiles staged one per
// phase (loads covered by ~4 phases of MFMA); ONE __syncthreads (vmcnt drain) per K-tile.
template <int BF>
__global__ __launch_bounds__(512, 2) void gemm256(const u16* __restrict__ A,
                                                  const u16* __restrict__ Bt,
                                                  const float* __restrict__ bproj,
                                                  u16* __restrict__ lat16,
                                                  float* __restrict__ latf,
                                                  float* __restrict__ psum,
                                                  float* __restrict__ psumsq) {
    extern __shared__ u16 dynlds[];
    const int t = threadIdx.x;
    const int wid = t >> 6;            // 0..7
    const int lane = t & 63;
    const int l16 = lane & 15;
    const int lk = lane >> 4;          // 0..3
    const int wm = wid >> 2;           // 0..1  (A half / 128-row block)
    const int wn = wid & 3;            // 0..3  (64-col block)

    // XCD-aware mapping: xcd owns 16 n-tiles; m fastest within -> B-slice L2-hot
    const int wg = blockIdx.x;
    const int xcd = wg & 7;
    const int local = wg >> 3;         // 0..255
    const int m0 = (local & 15) * 256;
    const int n0 = ((xcd << 4) + (local >> 4)) * 256;

    f32x4 acc[8][4];
    const f32x4 zero = {0.f, 0.f, 0.f, 0.f};
#pragma unroll
    for (int m = 0; m < 8; ++m)
#pragma unroll
        for (int n = 0; n < 4; ++n) acc[m][n] = zero;

    // stage half-tile p (0,1 = A halves; 2,3 = B halves) of K-tile ktn into buffer bn
    auto stage = [&](int p, int ktn, int bn) {
        const char* srcbase = (p < 2) ? (const char*)A : (const char*)Bt;
        const int rowbase = (p < 2) ? (m0 + p * 128) : (n0 + (p - 2) * 128);
        u16* ldsbase = dynlds + bn * 32768 + (p >> 1) * 16384 + (p & 1) * 8192;
#pragma unroll
        for (int i = 0; i < 2; ++i) {
            int oo = i * 8192 + t * 16;                  // byte off in 16KB half
            int oos = oo ^ (((oo >> 7) & 7) << 4);       // pre-swizzled source
            int row = oo >> 7;
            int colb = oos & 127;
            gl2lds16(srcbase + (size_t)(rowbase + row) * 2048 + ktn * 128 + colb,
                     ldsbase + i * 4096 + (wid << 9));   // wave-uniform dest (u16 units)
        }
    };

    // prologue: K-tile 0 into buf 0
#pragma unroll
    for (int p = 0; p < 4; ++p) stage(p, 0, 0);
    __syncthreads();

    const int swz = (l16 & 7) << 4;                      // read-side XOR (bytes)
    for (int kt = 0; kt < 16; ++kt) {
        const int buf = kt & 1;
        const char* aB = (const char*)(dynlds + buf * 32768 + wm * 8192);
        const char* bB = (const char*)(dynlds + buf * 32768 + 16384 + (wn >> 1) * 8192);
        bf16x8 bfr[4][2];
#pragma unroll
        for (int p = 0; p < 4; ++p) {
            if (kt < 15) stage(p, kt + 1, buf ^ 1);
            if (p == 0) {
#pragma unroll
                for (int nr = 0; nr < 4; ++nr)
#pragma unroll
                    for (int kk = 0; kk < 2; ++kk)
                        bfr[nr][kk] = *(const bf16x8*)(bB +
                            ((wn & 1) * 64 + nr * 16 + l16) * 128 +
                            ((kk * 64 + lk * 16) ^ swz));
            }
            bf16x8 afr[2][2];
#pragma unroll
            for (int mr = 0; mr < 2; ++mr)
#pragma unroll
                for (int kk = 0; kk < 2; ++kk)
                    afr[mr][kk] = *(const bf16x8*)(aB +
                        (p * 32 + mr * 16 + l16) * 128 +
                        ((kk * 64 + lk * 16) ^ swz));
            __builtin_amdgcn_s_setprio(1);
#pragma unroll
            for (int kk = 0; kk < 2; ++kk)
#pragma unroll
                for (int mr = 0; mr < 2; ++mr)
#pragma unroll
                    for (int nr = 0; nr < 4; ++nr)
                        acc[p * 2 + mr][nr] = __builtin_amdgcn_mfma_f32_16x16x32_bf16(
                            afr[mr][kk], bfr[nr][kk], acc[p * 2 + mr][nr], 0, 0, 0);
            __builtin_amdgcn_s_setprio(0);
        }
        __syncthreads();   // drain kt+1 stage loads; fence buf reuse
    }

    // ---- epilogue: bf16 latent store + LN partials (reuse dead buf0 LDS) ----
    float bias[4];
#pragma unroll
    for (int nr = 0; nr < 4; ++nr) bias[nr] = bproj[n0 + wn * 64 + nr * 16 + l16];

    float sm[8][4], s2[8][4];
#pragma unroll
    for (int mr = 0; mr < 8; ++mr)
#pragma unroll
        for (int j = 0; j < 4; ++j) { sm[mr][j] = 0.f; s2[mr][j] = 0.f; }

#pragma unroll
    for (int mr = 0; mr < 8; ++mr) {
#pragma unroll
        for (int j = 0; j < 4; ++j) {
            const int rowg = m0 + wm * 128 + mr * 16 + lk * 4 + j;
            size_t off = (size_t)rowg * NTOT + n0 + wn * 64 + l16;
#pragma unroll
            for (int nr = 0; nr < 4; ++nr) {
                float v = acc[mr][nr][j] + bias[nr];
                if (BF) lat16[off + nr * 16] = f2bf(v);
                else    latf[off + nr * 16] = v;
                sm[mr][j] += v;
                s2[mr][j] += v * v;
            }
        }
    }
#pragma unroll
    for (int o = 1; o < 16; o <<= 1) {
#pragma unroll
        for (int mr = 0; mr < 8; ++mr)
#pragma unroll
            for (int j = 0; j < 4; ++j) {
                sm[mr][j] += __shfl_xor(sm[mr][j], o);
                s2[mr][j] += __shfl_xor(s2[mr][j], o);
            }
    }
    float* sredf = (float*)dynlds;            // [4][256]  (aliases dead buf0)
    float* s2f   = sredf + 1024;              // [4][256]
    __syncthreads();
    if (l16 == 0) {
#pragma unroll
        for (int mr = 0; mr < 8; ++mr)
#pragma unroll
            for (int j = 0; j < 4; ++j) {
                int r = wm * 128 + mr * 16 + lk * 4 + j;
                sredf[wn * 256 + r] = sm[mr][j];
                s2f[wn * 256 + r] = s2[mr][j];
            }
    }
    __syncthreads();
    if (t < 256) {
        const int strip = n0 >> 8;
        float S = sredf[t] + sredf[256 + t] + sredf[512 + t] + sredf[768 + t];
        float S2 = s2f[t] + s2f[256 + t] + s2f[512 + t] + s2f[768 + t];
        psum[(size_t)strip * B_SZ + m0 + t] = S;
        psumsq[(size_t)strip * B_SZ + m0 + t] = S2;
    }
}

// ---------------- finalize LN stats from partials (psum layout [strip][b]) ----------------
__global__ __launch_bounds__(256) void ln_finalize(const float* __restrict__ psum,
                                                   const float* __restrict__ psumsq,
                                                   float* __restrict__ murs) {
    const int t = threadIdx.x;
    const int b0 = blockIdx.x * 64;
    const int tb = t & 63;            // which b
    const int tg = t >> 6;            // strip group 0..3
    float s = 0.f, s2 = 0.f;
    for (int sidx = tg; sidx < NSTRIP; sidx += 4) {
        s += psum[(size_t)sidx * B_SZ + b0 + tb];
        s2 += psumsq[(size_t)sidx * B_SZ + b0 + tb];
    }
    __shared__ float r1[4][64], r2[4][64];
    r1[tg][tb] = s;
    r2[tg][tb] = s2;
    __syncthreads();
    if (t < 64) {
        float S = r1[0][t] + r1[1][t] + r1[2][t] + r1[3][t];
        float S2 = r2[0][t] + r2[1][t] + r2[2][t] + r2[3][t];
        float m = S / (float)NTOT;
        float var = S2 / (float)NTOT - m * m;
        murs[b0 + t] = m;
        murs[B_SZ + b0 + t] = rsqrtf(var + LN_EPS);
    }
}

// ---------------- normalize + relu + heads: one 256-thread block per b ----------------
template <int BF>
__global__ __launch_bounds__(256) void headsG(const void* __restrict__ latin_,
                                              float* __restrict__ latout,
                                              const float* __restrict__ murs,
                                              const float* __restrict__ lnw,
                                              const float* __restrict__ lnb,
                                              const float* __restrict__ Wcat,
                                              const float* __restrict__ bcat,
                                              const float* __restrict__ Wcont,
                                              const float* __restrict__ bcont,
                                              float* __restrict__ pcat,
                                              float* __restrict__ pcont) {
    const int b = blockIdx.x;
    const int t = threadIdx.x;
    const int lane = t & 63;
    const int w4 = t >> 6;                    // wave 0..3
    const float mu = murs[b];
    const float rs = murs[B_SZ + b];
    const ushort4* lin16 = (const ushort4*)((const u16*)latin_ + (size_t)b * NTOT);
    const float4*  linf  = (const float4*)((const float*)latin_ + (size_t)b * NTOT);
    float4* lout4 = (float4*)(latout + (size_t)b * NTOT);
    const float4* lnw4 = (const float4*)lnw;
    const float4* lnb4 = (const float4*)lnb;
    const float4* wcont4 = (const float4*)Wcont;

    __shared__ float4 sy4[2][256];            // double-buffered head row of y
    __shared__ float cred[4][N_CAT][CAT_D];   // per-wave cat partials
    __shared__ float nred[N_CONT][4];         // per-wave cont partials

    // ---- categorical heads (k = h = 0..7) ----
    for (int k = 0; k < N_CAT; ++k) {
        const int i = (k << 8) + t;
        float4 x;
        if (BF) {
            ushort4 xv = lin16[i];
            x.x = bf2f(xv.x); x.y = bf2f(xv.y); x.z = bf2f(xv.z); x.w = bf2f(xv.w);
        } else {
            x = linf[i];
        }
        float4 w = lnw4[i];
        float4 bv = lnb4[i];
        float4 yo;
        yo.x = fmaxf(0.f, (x.x - mu) * rs * w.x + bv.x);
        yo.y = fmaxf(0.f, (x.y - mu) * rs * w.y + bv.y);
        yo.z = fmaxf(0.f, (x.z - mu) * rs * w.z + bv.z);
        yo.w = fmaxf(0.f, (x.w - mu) * rs * w.w + bv.w);
        lout4[i] = yo;
        sy4[k & 1][t] = yo;
        __syncthreads();

        const int c = t & 15;                 // category column
        const int g = t >> 4;                 // f-group: f = g*64 .. g*64+63
        const float* Wc = Wcat + (size_t)k * F_DIM * CAT_D + c;
        float acc = 0.f;
#pragma unroll
        for (int j = 0; j < 16; ++j) {
            float4 yv = sy4[k & 1][g * 16 + j];
            int fb = (g * 64 + j * 4) * CAT_D;
            acc += yv.x * Wc[fb] + yv.y * Wc[fb + CAT_D] +
                   yv.z * Wc[fb + 2 * CAT_D] + yv.w * Wc[fb + 3 * CAT_D];
        }
        acc += __shfl_xor(acc, 16);
        acc += __shfl_xor(acc, 32);
        if (lane < 16) cred[w4][k][lane] = acc;
    }

    // ---- continuous heads (k = 8..31): barrier-free streaming ----
#pragma unroll 2
    for (int k = N_CAT; k < H_NUM; ++k) {
        const int i = (k << 8) + t;
        float4 x;
        if (BF) {
            ushort4 xv = lin16[i];
            x.x = bf2f(xv.x); x.y = bf2f(xv.y); x.z = bf2f(xv.z); x.w = bf2f(xv.w);
        } else {
            x = linf[i];
        }
        float4 w = lnw4[i];
        float4 bv = lnb4[i];
        float4 wv = wcont4[((k - N_CAT) << 8) + t];
        float4 yo;
        yo.x = fmaxf(0.f, (x.x - mu) * rs * w.x + bv.x);
        yo.y = fmaxf(0.f, (x.y - mu) * rs * w.y + bv.y);
        yo.z = fmaxf(0.f, (x.z - mu) * rs * w.z + bv.z);
        yo.w = fmaxf(0.f, (x.w - mu) * rs * w.w + bv.w);
        lout4[i] = yo;
        float part = yo.x * wv.x + yo.y * wv.y + yo.z * wv.z + yo.w * wv.w;
        part = wave_sum(part);
        if (lane == 0) nred[k - N_CAT][w4] = part;
    }
    __syncthreads();

    // ---- finalize ----
    if (t < 128) {                            // cat softmax: h = t>>4, c = t&15
        const int h = t >> 4, c = t & 15;
        float lg = cred[0][h][c] + cred[1][h][c] + cred[2][h][c] + cred[3][h][c] +
                   bcat[h * CAT_D + c];
        float mx = lg;
#pragma unroll
        for (int o = 8; o; o >>= 1) mx = fmaxf(mx, __shfl_xor(mx, o, 16));
        float e = __expf(lg - mx);
        float sm2 = e;
#pragma unroll
        for (int o = 8; o; o >>= 1) sm2 += __shfl_xor(sm2, o, 16);
        pcat[(size_t)b * (N_CAT * CAT_D) + t] = e / sm2;
    } else if (t >= 128 && t < 128 + N_CONT) {
        const int ci = t - 128;
        pcont[(size_t)b * N_CONT + ci] =
            nred[ci][0] + nred[ci][1] + nred[ci][2] + nred[ci][3] + bcont[ci];
    }
}

extern "C" void kernel_launch(void* const* d_in, const int* in_sizes, int n_in,
                              void* d_out, int out_size, void* d_ws, size_t ws_size,
                              hipStream_t stream) {
    const float* z     = (const float*)d_in[0];
    // d_in[1] = edge (unused by reference computation)
    const float* Wp    = (const float*)d_in[2];
    const float* bp    = (const float*)d_in[3];
    const float* lnw   = (const float*)d_in[4];
    const float* lnb   = (const float*)d_in[5];
    const float* Wcat  = (const float*)d_in[6];
    const float* bcat  = (const float*)d_in[7];
    const float* Wcont = (const float*)d_in[8];
    const float* bcont = (const float*)d_in[9];

    float* out    = (float*)d_out;
    float* pcat   = out;                                   // [4096, 8, 16]
    float* pcont  = out + (size_t)B_SZ * N_CAT * CAT_D;    // [4096, 24, 1]
    float* latent = pcont + (size_t)B_SZ * N_CONT;         // [4096, 32, 1024]

    u16* zb     = (u16*)d_ws;                              // 8 MB
    u16* Wt     = zb + (size_t)B_SZ * F_DIM;               // 64 MB
    float* murs = (float*)(Wt + (size_t)NTOT * F_DIM);     // 32 KB
    float* psum   = murs + 2 * B_SZ;                       // [128][4096] 2 MB
    float* psumsq = psum + (size_t)B_SZ * NSTRIP;          // 2 MB
    u16* lat16  = (u16*)(psumsq + (size_t)B_SZ * NSTRIP);  // 256 MB (optional)

    const size_t need = (size_t)((char*)(lat16 + (size_t)B_SZ * NTOT) - (char*)d_ws);
    const bool usebf = ws_size >= need;

    const int LDSB = 131072;
    zconv<<<dim3(B_SZ * F_DIM / 1024), 256, 0, stream>>>(z, zb);
    transpose_w<<<dim3(16, 16, 32), 256, 0, stream>>>(Wp, Wt);
    if (usebf) {
        (void)hipFuncSetAttribute((const void*)gemm256<1>,
                                  hipFuncAttributeMaxDynamicSharedMemorySize, LDSB);
        gemm256<1><<<dim3(2048), 512, LDSB, stream>>>(zb, Wt, bp, lat16, nullptr,
                                                      psum, psumsq);
        ln_finalize<<<dim3(B_SZ / 64), 256, 0, stream>>>(psum, psumsq, murs);
        headsG<1><<<dim3(B_SZ), 256, 0, stream>>>(lat16, latent, murs, lnw, lnb,
                                                  Wcat, bcat, Wcont, bcont, pcat, pcont);
    } else {
        (void)hipFuncSetAttribute((const void*)gemm256<0>,
                                  hipFuncAttributeMaxDynamicSharedMemorySize, LDSB);
        gemm256<0><<<dim3(2048), 512, LDSB, stream>>>(zb, Wt, bp, nullptr, latent,
                                                      psum, psumsq);
        ln_finalize<<<dim3(B_SZ / 64), 256, 0, stream>>>(psum, psumsq, murs);
        headsG<0><<<dim3(B_SZ), 256, 0, stream>>>(latent, latent, murs, lnw, lnb,
                                                  Wcat, bcat, Wcont, bcont, pcat, pcont);
    }
}

// Round 10
// 745.679 us; speedup vs baseline: 1.3744x; 1.0209x over previous
//
#include <hip/hip_runtime.h>

typedef unsigned short u16;
typedef __bf16 bf16x8 __attribute__((ext_vector_type(8)));
typedef float f32x4 __attribute__((ext_vector_type(4)));

#define B_SZ   4096
#define H_NUM  32
#define F_DIM  1024
#define NTOT   (H_NUM * F_DIM)   // 32768
#define N_CAT  8
#define CAT_D  16
#define N_CONT 24
#define LN_EPS 1e-5f
#define NSTRIP 128               // 256-col strips in the 256^2 GEMM

__device__ __forceinline__ u16 f2bf(float f) {
    unsigned int u = __builtin_bit_cast(unsigned int, f);
    unsigned int r = (u + 0x7FFFu + ((u >> 16) & 1u)) >> 16;
    return (u16)r;
}

__device__ __forceinline__ float bf2f(u16 v) {
    unsigned int u = ((unsigned int)v) << 16;
    return __builtin_bit_cast(float, u);
}

__device__ __forceinline__ void gl2lds16(const void* g, void* l) {
    __builtin_amdgcn_global_load_lds(
        (const __attribute__((address_space(1))) void*)g,
        (__attribute__((address_space(3))) void*)l,
        16, 0, 0);
}

__device__ __forceinline__ float wave_sum(float v) {
#pragma unroll
    for (int o = 32; o; o >>= 1) v += __shfl_xor(v, o);
    return v;
}

// ---------------- z f32 -> bf16 ----------------
__global__ __launch_bounds__(256) void zconv(const float* __restrict__ z,
                                             u16* __restrict__ zb) {
    int i = blockIdx.x * 256 + threadIdx.x;      // one float4 per thread
    float4 v = ((const float4*)z)[i];
    ushort4 o;
    o.x = f2bf(v.x); o.y = f2bf(v.y); o.z = f2bf(v.z); o.w = f2bf(v.w);
    ((ushort4*)zb)[i] = o;
}

// ---------------- W_proj [h][f][d] f32 -> Wt [h][d][f] bf16 ----------------
__global__ __launch_bounds__(256) void transpose_w(const float* __restrict__ W,
                                                   u16* __restrict__ Wt) {
    __shared__ u16 tile[64][72];
    const int h = blockIdx.z;
    const int f0 = blockIdx.x * 64;
    const int d0 = blockIdx.y * 64;
    const float* Wh = W + (size_t)h * F_DIM * F_DIM;
    u16* Wth = Wt + (size_t)h * F_DIM * F_DIM;
    const int t = threadIdx.x;

#pragma unroll
    for (int i = 0; i < 4; ++i) {
        int idx = i * 256 + t;        // 0..1023
        int fr = idx >> 4;            // 0..63
        int c4 = idx & 15;            // 0..15
        float4 v = *(const float4*)(Wh + (size_t)(f0 + fr) * F_DIM + d0 + c4 * 4);
        tile[fr][c4 * 4 + 0] = f2bf(v.x);
        tile[fr][c4 * 4 + 1] = f2bf(v.y);
        tile[fr][c4 * 4 + 2] = f2bf(v.z);
        tile[fr][c4 * 4 + 3] = f2bf(v.w);
    }
    __syncthreads();
#pragma unroll
    for (int i = 0; i < 2; ++i) {
        int idx = i * 256 + t;        // 0..511
        int dr = idx >> 3;            // 0..63
        int c8 = idx & 7;             // 0..7
        __attribute__((aligned(16))) u16 tmp[8];
#pragma unroll
        for (int j = 0; j < 8; ++j) tmp[j] = tile[c8 * 8 + j][dr];
        *(uint4*)(Wth + (size_t)(d0 + dr) * F_DIM + f0 + c8 * 8) = *(const uint4*)tmp;
    }
}

// ---------------- GEMM 256^2, 8 waves, 2-Ktile LDS dbuf, XOR-swizzled ----------------
// (unchanged from R9 — verified 495 -> ~325 us)
template <int BF>
__global__ __launch_bounds__(512, 2) void gemm256(const u16* __restrict__ A,
                                                  const u16* __restrict__ Bt,
                                                  const float* __restrict__ bproj,
                                                  u16* __restrict__ lat16,
                                                  float* __restrict__ latf,
                                                  float* __restrict__ psum,
                                                  float* __restrict__ psumsq) {
    extern __shared__ u16 dynlds[];
    const int t = threadIdx.x;
    const int wid = t >> 6;            // 0..7
    const int lane = t & 63;
    const int l16 = lane & 15;
    const int lk = lane >> 4;          // 0..3
    const int wm = wid >> 2;           // 0..1  (A half / 128-row block)
    const int wn = wid & 3;            // 0..3  (64-col block)

    const int wg = blockIdx.x;
    const int xcd = wg & 7;
    const int local = wg >> 3;         // 0..255
    const int m0 = (local & 15) * 256;
    const int n0 = ((xcd << 4) + (local >> 4)) * 256;

    f32x4 acc[8][4];
    const f32x4 zero = {0.f, 0.f, 0.f, 0.f};
#pragma unroll
    for (int m = 0; m < 8; ++m)
#pragma unroll
        for (int n = 0; n < 4; ++n) acc[m][n] = zero;

    auto stage = [&](int p, int ktn, int bn) {
        const char* srcbase = (p < 2) ? (const char*)A : (const char*)Bt;
        const int rowbase = (p < 2) ? (m0 + p * 128) : (n0 + (p - 2) * 128);
        u16* ldsbase = dynlds + bn * 32768 + (p >> 1) * 16384 + (p & 1) * 8192;
#pragma unroll
        for (int i = 0; i < 2; ++i) {
            int oo = i * 8192 + t * 16;                  // byte off in 16KB half
            int oos = oo ^ (((oo >> 7) & 7) << 4);       // pre-swizzled source
            int row = oo >> 7;
            int colb = oos & 127;
            gl2lds16(srcbase + (size_t)(rowbase + row) * 2048 + ktn * 128 + colb,
                     ldsbase + i * 4096 + (wid << 9));   // wave-uniform dest (u16 units)
        }
    };

#pragma unroll
    for (int p = 0; p < 4; ++p) stage(p, 0, 0);
    __syncthreads();

    const int swz = (l16 & 7) << 4;                      // read-side XOR (bytes)
    for (int kt = 0; kt < 16; ++kt) {
        const int buf = kt & 1;
        const char* aB = (const char*)(dynlds + buf * 32768 + wm * 8192);
        const char* bB = (const char*)(dynlds + buf * 32768 + 16384 + (wn >> 1) * 8192);
        bf16x8 bfr[4][2];
#pragma unroll
        for (int p = 0; p < 4; ++p) {
            if (kt < 15) stage(p, kt + 1, buf ^ 1);
            if (p == 0) {
#pragma unroll
                for (int nr = 0; nr < 4; ++nr)
#pragma unroll
                    for (int kk = 0; kk < 2; ++kk)
                        bfr[nr][kk] = *(const bf16x8*)(bB +
                            ((wn & 1) * 64 + nr * 16 + l16) * 128 +
                            ((kk * 64 + lk * 16) ^ swz));
            }
            bf16x8 afr[2][2];
#pragma unroll
            for (int mr = 0; mr < 2; ++mr)
#pragma unroll
                for (int kk = 0; kk < 2; ++kk)
                    afr[mr][kk] = *(const bf16x8*)(aB +
                        (p * 32 + mr * 16 + l16) * 128 +
                        ((kk * 64 + lk * 16) ^ swz));
            __builtin_amdgcn_s_setprio(1);
#pragma unroll
            for (int kk = 0; kk < 2; ++kk)
#pragma unroll
                for (int mr = 0; mr < 2; ++mr)
#pragma unroll
                    for (int nr = 0; nr < 4; ++nr)
                        acc[p * 2 + mr][nr] = __builtin_amdgcn_mfma_f32_16x16x32_bf16(
                            afr[mr][kk], bfr[nr][kk], acc[p * 2 + mr][nr], 0, 0, 0);
            __builtin_amdgcn_s_setprio(0);
        }
        __syncthreads();   // drain kt+1 stage loads; fence buf reuse
    }

    // ---- epilogue: bf16 latent store + LN partials (reuse dead buf0 LDS) ----
    float bias[4];
#pragma unroll
    for (int nr = 0; nr < 4; ++nr) bias[nr] = bproj[n0 + wn * 64 + nr * 16 + l16];

    float sm[8][4], s2[8][4];
#pragma unroll
    for (int mr = 0; mr < 8; ++mr)
#pragma unroll
        for (int j = 0; j < 4; ++j) { sm[mr][j] = 0.f; s2[mr][j] = 0.f; }

#pragma unroll
    for (int mr = 0; mr < 8; ++mr) {
#pragma unroll
        for (int j = 0; j < 4; ++j) {
            const int rowg = m0 + wm * 128 + mr * 16 + lk * 4 + j;
            size_t off = (size_t)rowg * NTOT + n0 + wn * 64 + l16;
#pragma unroll
            for (int nr = 0; nr < 4; ++nr) {
                float v = acc[mr][nr][j] + bias[nr];
                if (BF) lat16[off + nr * 16] = f2bf(v);
                else    latf[off + nr * 16] = v;
                sm[mr][j] += v;
                s2[mr][j] += v * v;
            }
        }
    }
#pragma unroll
    for (int o = 1; o < 16; o <<= 1) {
#pragma unroll
        for (int mr = 0; mr < 8; ++mr)
#pragma unroll
            for (int j = 0; j < 4; ++j) {
                sm[mr][j] += __shfl_xor(sm[mr][j], o);
                s2[mr][j] += __shfl_xor(s2[mr][j], o);
            }
    }
    float* sredf = (float*)dynlds;            // [4][256]  (aliases dead buf0)
    float* s2f   = sredf + 1024;              // [4][256]
    __syncthreads();
    if (l16 == 0) {
#pragma unroll
        for (int mr = 0; mr < 8; ++mr)
#pragma unroll
            for (int j = 0; j < 4; ++j) {
                int r = wm * 128 + mr * 16 + lk * 4 + j;
                sredf[wn * 256 + r] = sm[mr][j];
                s2f[wn * 256 + r] = s2[mr][j];
            }
    }
    __syncthreads();
    if (t < 256) {
        const int strip = n0 >> 8;
        float S = sredf[t] + sredf[256 + t] + sredf[512 + t] + sredf[768 + t];
        float S2 = s2f[t] + s2f[256 + t] + s2f[512 + t] + s2f[768 + t];
        psum[(size_t)strip * B_SZ + m0 + t] = S;
        psumsq[(size_t)strip * B_SZ + m0 + t] = S2;
    }
}

// ---------------- finalize LN stats from partials (psum layout [strip][b]) ----------------
__global__ __launch_bounds__(256) void ln_finalize(const float* __restrict__ psum,
                                                   const float* __restrict__ psumsq,
                                                   float* __restrict__ murs) {
    const int t = threadIdx.x;
    const int b0 = blockIdx.x * 64;
    const int tb = t & 63;            // which b
    const int tg = t >> 6;            // strip group 0..3
    float s = 0.f, s2 = 0.f;
    for (int sidx = tg; sidx < NSTRIP; sidx += 4) {
        s += psum[(size_t)sidx * B_SZ + b0 + tb];
        s2 += psumsq[(size_t)sidx * B_SZ + b0 + tb];
    }
    __shared__ float r1[4][64], r2[4][64];
    r1[tg][tb] = s;
    r2[tg][tb] = s2;
    __syncthreads();
    if (t < 64) {
        float S = r1[0][t] + r1[1][t] + r1[2][t] + r1[3][t];
        float S2 = r2[0][t] + r2[1][t] + r2[2][t] + r2[3][t];
        float m = S / (float)NTOT;
        float var = S2 / (float)NTOT - m * m;
        murs[b0 + t] = m;
        murs[B_SZ + b0 + t] = rsqrtf(var + LN_EPS);
    }
}

// ---------------- normalize + relu + heads: one 256-thread block per b ----------------
// Restructured to 2 barriers total:
//   Phase 1 (barrier-free stream, all 32 heads): load lat16, normalize, store latent;
//     cat heads (k<8) also stage bf16 y into own LDS slot; cont heads just assign a
//     per-thread dot partial cp[k-8] (no shuffles in the stream).
//   Barrier. Phase 2: 8 cat GEMVs from LDS (c=t&15, 2 shfl each) + batched reduce of
//     the 24 cont partials. Barrier. Phase 3: softmax + pcont finalize.
template <int BF>
__global__ __launch_bounds__(256) void headsH(const void* __restrict__ latin_,
                                              float* __restrict__ latout,
                                              const float* __restrict__ murs,
                                              const float* __restrict__ lnw,
                                              const float* __restrict__ lnb,
                                              const float* __restrict__ Wcat,
                                              const float* __restrict__ bcat,
                                              const float* __restrict__ Wcont,
                                              const float* __restrict__ bcont,
                                              float* __restrict__ pcat,
                                              float* __restrict__ pcont) {
    const int b = blockIdx.x;
    const int t = threadIdx.x;
    const int lane = t & 63;
    const int w4 = t >> 6;                    // wave 0..3
    const float mu = murs[b];
    const float rs = murs[B_SZ + b];
    const ushort4* lin16 = (const ushort4*)((const u16*)latin_ + (size_t)b * NTOT);
    const float4*  linf  = (const float4*)((const float*)latin_ + (size_t)b * NTOT);
    float4* lout4 = (float4*)(latout + (size_t)b * NTOT);
    const float4* lnw4 = (const float4*)lnw;
    const float4* lnb4 = (const float4*)lnb;
    const float4* wcont4 = (const float4*)Wcont;

    __shared__ ushort4 sy16[N_CAT * 256];     // 8 heads' y, bf16 (16 KB)
    __shared__ float cred[4][N_CAT][CAT_D];   // per-wave cat partials
    __shared__ float nred[N_CONT][4];         // per-wave cont partials

    // ---- phase 1a: cat heads — normalize, store, stage y (no barriers) ----
#pragma unroll 2
    for (int k = 0; k < N_CAT; ++k) {
        const int i = (k << 8) + t;
        float4 x;
        if (BF) {
            ushort4 xv = lin16[i];
            x.x = bf2f(xv.x); x.y = bf2f(xv.y); x.z = bf2f(xv.z); x.w = bf2f(xv.w);
        } else {
            x = linf[i];
        }
        float4 w = lnw4[i];
        float4 bv = lnb4[i];
        float4 yo;
        yo.x = fmaxf(0.f, (x.x - mu) * rs * w.x + bv.x);
        yo.y = fmaxf(0.f, (x.y - mu) * rs * w.y + bv.y);
        yo.z = fmaxf(0.f, (x.z - mu) * rs * w.z + bv.z);
        yo.w = fmaxf(0.f, (x.w - mu) * rs * w.w + bv.w);
        lout4[i] = yo;
        ushort4 ys;
        ys.x = f2bf(yo.x); ys.y = f2bf(yo.y); ys.z = f2bf(yo.z); ys.w = f2bf(yo.w);
        sy16[i] = ys;                          // own slot, no race
    }

    // ---- phase 1b: cont heads — pure streaming, per-thread partial only ----
    float cp[N_CONT];
#pragma unroll 2
    for (int k = N_CAT; k < H_NUM; ++k) {
        const int i = (k << 8) + t;
        float4 x;
        if (BF) {
            ushort4 xv = lin16[i];
            x.x = bf2f(xv.x); x.y = bf2f(xv.y); x.z = bf2f(xv.z); x.w = bf2f(xv.w);
        } else {
            x = linf[i];
        }
        float4 w = lnw4[i];
        float4 bv = lnb4[i];
        float4 wv = wcont4[((k - N_CAT) << 8) + t];
        float4 yo;
        yo.x = fmaxf(0.f, (x.x - mu) * rs * w.x + bv.x);
        yo.y = fmaxf(0.f, (x.y - mu) * rs * w.y + bv.y);
        yo.z = fmaxf(0.f, (x.z - mu) * rs * w.z + bv.z);
        yo.w = fmaxf(0.f, (x.w - mu) * rs * w.w + bv.w);
        lout4[i] = yo;
        cp[k - N_CAT] = yo.x * wv.x + yo.y * wv.y + yo.z * wv.z + yo.w * wv.w;
    }
    __syncthreads();

    // ---- phase 2a: cat GEMVs from LDS (c = t&15, f-group g = t>>4) ----
    const int c = t & 15;
    const int g = t >> 4;
    for (int k = 0; k < N_CAT; ++k) {
        const float* Wc = Wcat + (size_t)k * F_DIM * CAT_D + c;
        float acc = 0.f;
#pragma unroll
        for (int j = 0; j < 16; ++j) {
            ushort4 yv = sy16[(k << 8) + g * 16 + j];
            int fb = (g * 64 + j * 4) * CAT_D;
            acc += bf2f(yv.x) * Wc[fb] + bf2f(yv.y) * Wc[fb + CAT_D] +
                   bf2f(yv.z) * Wc[fb + 2 * CAT_D] + bf2f(yv.w) * Wc[fb + 3 * CAT_D];
        }
        acc += __shfl_xor(acc, 16);
        acc += __shfl_xor(acc, 32);
        if (lane < 16) cred[w4][k][lane] = acc;   // lane == c here
    }
    // ---- phase 2b: batched cont reduce (once per block, not per stream-iter) ----
#pragma unroll
    for (int k = 0; k < N_CONT; ++k) {
        float v = wave_sum(cp[k]);
        if (lane == 0) nred[k][w4] = v;
    }
    __syncthreads();

    // ---- phase 3: finalize ----
    if (t < 128) {                            // cat softmax: h = t>>4, c = t&15
        const int h = t >> 4, cc = t & 15;
        float lg = cred[0][h][cc] + cred[1][h][cc] + cred[2][h][cc] + cred[3][h][cc] +
                   bcat[h * CAT_D + cc];
        float mx = lg;
#pragma unroll
        for (int o = 8; o; o >>= 1) mx = fmaxf(mx, __shfl_xor(mx, o, 16));
        float e = __expf(lg - mx);
        float sm2 = e;
#pragma unroll
        for (int o = 8; o; o >>= 1) sm2 += __shfl_xor(sm2, o, 16);
        pcat[(size_t)b * (N_CAT * CAT_D) + t] = e / sm2;
    } else if (t >= 128 && t < 128 + N_CONT) {
        const int ci = t - 128;
        pcont[(size_t)b * N_CONT + ci] =
            nred[ci][0] + nred[ci][1] + nred[ci][2] + nred[ci][3] + bcont[ci];
    }
}

extern "C" void kernel_launch(void* const* d_in, const int* in_sizes, int n_in,
                              void* d_out, int out_size, void* d_ws, size_t ws_size,
                              hipStream_t stream) {
    const float* z     = (const float*)d_in[0];
    // d_in[1] = edge (unused by reference computation)
    const float* Wp    = (const float*)d_in[2];
    const float* bp    = (const float*)d_in[3];
    const float* lnw   = (const float*)d_in[4];
    const float* lnb   = (const float*)d_in[5];
    const float* Wcat  = (const float*)d_in[6];
    const float* bcat  = (const float*)d_in[7];
    const float* Wcont = (const float*)d_in[8];
    const float* bcont = (const float*)d_in[9];

    float* out    = (float*)d_out;
    float* pcat   = out;                                   // [4096, 8, 16]
    float* pcont  = out + (size_t)B_SZ * N_CAT * CAT_D;    // [4096, 24, 1]
    float* latent = pcont + (size_t)B_SZ * N_CONT;         // [4096, 32, 1024]

    u16* zb     = (u16*)d_ws;                              // 8 MB
    u16* Wt     = zb + (size_t)B_SZ * F_DIM;               // 64 MB
    float* murs = (float*)(Wt + (size_t)NTOT * F_DIM);     // 32 KB
    float* psum   = murs + 2 * B_SZ;                       // [128][4096] 2 MB
    float* psumsq = psum + (size_t)B_SZ * NSTRIP;          // 2 MB
    u16* lat16  = (u16*)(psumsq + (size_t)B_SZ * NSTRIP);  // 256 MB (optional)

    const size_t need = (size_t)((char*)(lat16 + (size_t)B_SZ * NTOT) - (char*)d_ws);
    const bool usebf = ws_size >= need;

    const int LDSB = 131072;
    zconv<<<dim3(B_SZ * F_DIM / 1024), 256, 0, stream>>>(z, zb);
    transpose_w<<<dim3(16, 16, 32), 256, 0, stream>>>(Wp, Wt);
    if (usebf) {
        (void)hipFuncSetAttribute((const void*)gemm256<1>,
                                  hipFuncAttributeMaxDynamicSharedMemorySize, LDSB);
        gemm256<1><<<dim3(2048), 512, LDSB, stream>>>(zb, Wt, bp, lat16, nullptr,
                                                      psum, psumsq);
        ln_finalize<<<dim3(B_SZ / 64), 256, 0, stream>>>(psum, psumsq, murs);
        headsH<1><<<dim3(B_SZ), 256, 0, stream>>>(lat16, latent, murs, lnw, lnb,
                                                  Wcat, bcat, Wcont, bcont, pcat, pcont);
    } else {
        (void)hipFuncSetAttribute((const void*)gemm256<0>,
                                  hipFuncAttributeMaxDynamicSharedMemorySize, LDSB);
        gemm256<0><<<dim3(2048), 512, LDSB, stream>>>(zb, Wt, bp, nullptr, latent,
                                                      psum, psumsq);
        ln_finalize<<<dim3(B_SZ / 64), 256, 0, stream>>>(psum, psumsq, murs);
        headsH<0><<<dim3(B_SZ), 256, 0, stream>>>(latent, latent, murs, lnw, lnb,
                                                  Wcat, bcat, Wcont, bcont, pcat, pcont);
    }
}